// Round 1
// baseline (198.103 us; speedup 1.0000x reference)
//
#include <hip/hip_runtime.h>
#include <hip/hip_bf16.h>

typedef __attribute__((ext_vector_type(8))) short bf16x8;
typedef __attribute__((ext_vector_type(4))) float f32x4;

#define MFMA16(a, b, c) __builtin_amdgcn_mfma_f32_16x16x32_bf16((a), (b), (c), 0, 0, 0)

static constexpr int BATCH = 4, S = 2048, DMODEL = 512, H = 8, HD = 64;
static constexpr int M = BATCH * S;  // 8192

// round-to-nearest-even f32 -> bf16 (bit trick; inputs finite)
__device__ __forceinline__ short f2b(float f) {
  unsigned int u = __builtin_bit_cast(unsigned int, f);
  unsigned int r = (u + 0x7fffu + ((u >> 16) & 1u)) >> 16;
  return (short)r;
}

__device__ __forceinline__ bf16x8 cvt8(const float4& a, const float4& b) {
  bf16x8 r;
  r[0] = f2b(a.x); r[1] = f2b(a.y); r[2] = f2b(a.z); r[3] = f2b(a.w);
  r[4] = f2b(b.x); r[5] = f2b(b.y); r[6] = f2b(b.z); r[7] = f2b(b.w);
  return r;
}

// ---------------- weight fp32 -> bf16 ----------------
__global__ __launch_bounds__(256) void convert_w(
    const float* __restrict__ Wq, const float* __restrict__ Wk,
    const float* __restrict__ Wv, const float* __restrict__ Wo,
    short* __restrict__ Wb) {
  const float* src = (blockIdx.y == 0) ? Wq : (blockIdx.y == 1) ? Wk
                   : (blockIdx.y == 2) ? Wv : Wo;
  short* dst = Wb + blockIdx.y * (DMODEL * DMODEL);
  int i = (blockIdx.x * 256 + threadIdx.x) * 8;
  float4 a = *(const float4*)&src[i];
  float4 b = *(const float4*)&src[i + 4];
  *(bf16x8*)&dst[i] = cvt8(a, b);
}

// ---------------- fused Q/K/V projection: C = A @ W^T + b, scatter [B,H,S,HD] bf16 ----------------
__global__ __launch_bounds__(256) void proj_gemm(
    const float* __restrict__ Aq, const float* __restrict__ Ak, const float* __restrict__ Av,
    const short* __restrict__ Wb,
    const float* __restrict__ bq, const float* __restrict__ bk, const float* __restrict__ bv,
    short* __restrict__ Qp, short* __restrict__ Kp, short* __restrict__ Vp) {
  const int which = blockIdx.y;
  const float* A    = (which == 0) ? Aq : (which == 1) ? Ak : Av;
  const short* W    = Wb + which * (DMODEL * DMODEL);
  const float* bias = (which == 0) ? bq : (which == 1) ? bk : bv;
  short* dst        = (which == 0) ? Qp : (which == 1) ? Kp : Vp;

  const int tm = blockIdx.x & 63;   // M/128 = 64
  const int tn = blockIdx.x >> 6;   // N/128 = 4
  const int m0 = tm * 128, n0 = tn * 128;
  const int t = threadIdx.x;
  const int lane = t & 63, w = t >> 6;
  const int g = lane >> 4, c = lane & 15;
  const int wr = w >> 1, wc = w & 1;

  __shared__ __align__(16) short As[128 * 32];
  __shared__ __align__(16) short Bs[128 * 32];

  f32x4 acc[4][4];
  const f32x4 fz = {0.f, 0.f, 0.f, 0.f};
#pragma unroll
  for (int i = 0; i < 4; ++i)
#pragma unroll
    for (int j = 0; j < 4; ++j) acc[i][j] = fz;

  const int r0 = t >> 2, c0 = (t & 3) * 8;
  const int r1 = (t + 256) >> 2;

  for (int kt = 0; kt < DMODEL / 32; ++kt) {
    const int k0 = kt * 32;
    float4 a0 = *(const float4*)&A[(m0 + r0) * DMODEL + k0 + c0];
    float4 a1 = *(const float4*)&A[(m0 + r0) * DMODEL + k0 + c0 + 4];
    float4 a2 = *(const float4*)&A[(m0 + r1) * DMODEL + k0 + c0];
    float4 a3 = *(const float4*)&A[(m0 + r1) * DMODEL + k0 + c0 + 4];
    bf16x8 b0 = *(const bf16x8*)&W[(n0 + r0) * DMODEL + k0 + c0];
    bf16x8 b1 = *(const bf16x8*)&W[(n0 + r1) * DMODEL + k0 + c0];
    __syncthreads();
    *(bf16x8*)&As[t * 8]        = cvt8(a0, a1);
    *(bf16x8*)&As[t * 8 + 2048] = cvt8(a2, a3);
    *(bf16x8*)&Bs[t * 8]        = b0;
    *(bf16x8*)&Bs[t * 8 + 2048] = b1;
    __syncthreads();
    bf16x8 af[4], bfr[4];
#pragma unroll
    for (int i = 0; i < 4; ++i)
      af[i] = *(const bf16x8*)&As[(wr * 64 + i * 16 + c) * 32 + g * 8];
#pragma unroll
    for (int j = 0; j < 4; ++j)
      bfr[j] = *(const bf16x8*)&Bs[(wc * 64 + j * 16 + c) * 32 + g * 8];
#pragma unroll
    for (int i = 0; i < 4; ++i)
#pragma unroll
      for (int j = 0; j < 4; ++j)
        acc[i][j] = MFMA16(af[i], bfr[j], acc[i][j]);
  }

#pragma unroll
  for (int i = 0; i < 4; ++i) {
#pragma unroll
    for (int j = 0; j < 4; ++j) {
      const int n = n0 + wc * 64 + j * 16 + c;
      const int h = n >> 6, hd = n & 63;
      const float bn = bias[n];
#pragma unroll
      for (int r = 0; r < 4; ++r) {
        const int m = m0 + wr * 64 + i * 16 + g * 4 + r;
        const int bb = m >> 11, s = m & (S - 1);
        dst[((bb * H + h) * S + s) * HD + hd] = f2b(acc[i][j][r] + bn);
      }
    }
  }
}

// ---------------- output GEMM: Out = att @ Wo^T + bo (fp32 out) ----------------
__global__ __launch_bounds__(256) void out_gemm(
    const short* __restrict__ Am, const short* __restrict__ W,
    const float* __restrict__ bias, float* __restrict__ Out) {
  const int tm = blockIdx.x & 63;
  const int tn = blockIdx.x >> 6;
  const int m0 = tm * 128, n0 = tn * 128;
  const int t = threadIdx.x;
  const int lane = t & 63, w = t >> 6;
  const int g = lane >> 4, c = lane & 15;
  const int wr = w >> 1, wc = w & 1;

  __shared__ __align__(16) short As[128 * 32];
  __shared__ __align__(16) short Bs[128 * 32];

  f32x4 acc[4][4];
  const f32x4 fz = {0.f, 0.f, 0.f, 0.f};
#pragma unroll
  for (int i = 0; i < 4; ++i)
#pragma unroll
    for (int j = 0; j < 4; ++j) acc[i][j] = fz;

  const int r0 = t >> 2, c0 = (t & 3) * 8;
  const int r1 = (t + 256) >> 2;

  for (int kt = 0; kt < DMODEL / 32; ++kt) {
    const int k0 = kt * 32;
    bf16x8 a0 = *(const bf16x8*)&Am[(m0 + r0) * DMODEL + k0 + c0];
    bf16x8 a1 = *(const bf16x8*)&Am[(m0 + r1) * DMODEL + k0 + c0];
    bf16x8 b0 = *(const bf16x8*)&W[(n0 + r0) * DMODEL + k0 + c0];
    bf16x8 b1 = *(const bf16x8*)&W[(n0 + r1) * DMODEL + k0 + c0];
    __syncthreads();
    *(bf16x8*)&As[t * 8]        = a0;
    *(bf16x8*)&As[t * 8 + 2048] = a1;
    *(bf16x8*)&Bs[t * 8]        = b0;
    *(bf16x8*)&Bs[t * 8 + 2048] = b1;
    __syncthreads();
    bf16x8 af[4], bfr[4];
#pragma unroll
    for (int i = 0; i < 4; ++i)
      af[i] = *(const bf16x8*)&As[(wr * 64 + i * 16 + c) * 32 + g * 8];
#pragma unroll
    for (int j = 0; j < 4; ++j)
      bfr[j] = *(const bf16x8*)&Bs[(wc * 64 + j * 16 + c) * 32 + g * 8];
#pragma unroll
    for (int i = 0; i < 4; ++i)
#pragma unroll
      for (int j = 0; j < 4; ++j)
        acc[i][j] = MFMA16(af[i], bfr[j], acc[i][j]);
  }

#pragma unroll
  for (int i = 0; i < 4; ++i) {
#pragma unroll
    for (int j = 0; j < 4; ++j) {
      const int n = n0 + wc * 64 + j * 16 + c;
      const float bn = bias[n];
#pragma unroll
      for (int r = 0; r < 4; ++r) {
        const int m = m0 + wr * 64 + i * 16 + g * 4 + r;
        Out[m * DMODEL + n] = acc[i][j][r] + bn;
      }
    }
  }
}

// ---------------- flash attention: per (b,h,q-tile of 128), 4 waves x 32 q-rows ----------------
__global__ __launch_bounds__(256) void attn_kernel(
    const short* __restrict__ Qp, const short* __restrict__ Kp,
    const short* __restrict__ Vp, short* __restrict__ att) {
  const int qt = blockIdx.x & 15;
  const int bh = blockIdx.x >> 4;        // b*H + h
  const int b = bh >> 3, h = bh & 7;
  const short* Q = Qp + bh * S * HD;
  const short* K = Kp + bh * S * HD;
  const short* V = Vp + bh * S * HD;

  const int t = threadIdx.x;
  const int lane = t & 63, w = t >> 6;
  const int g = lane >> 4, c = lane & 15;
  const int q0 = qt * 128 + w * 32;

  __shared__ __align__(16) short Vt[64 * 72];      // V^T tile: [d][kk], pitch 72
  __shared__ __align__(16) short Pl[4][32 * 72];   // per-wave P tile: [qrow][kk], pitch 72

  // Q fragments (hoisted for the whole block)
  bf16x8 qf[2][2];
#pragma unroll
  for (int mt = 0; mt < 2; ++mt)
#pragma unroll
    for (int ks = 0; ks < 2; ++ks)
      qf[mt][ks] = *(const bf16x8*)&Q[(q0 + mt * 16 + c) * HD + ks * 32 + g * 8];

  f32x4 o[2][4];
  float mst[2][4], lst[2][4];
  const f32x4 fz = {0.f, 0.f, 0.f, 0.f};
#pragma unroll
  for (int mt = 0; mt < 2; ++mt) {
#pragma unroll
    for (int nt = 0; nt < 4; ++nt) o[mt][nt] = fz;
#pragma unroll
    for (int r = 0; r < 4; ++r) { mst[mt][r] = -1e30f; lst[mt][r] = 0.f; }
  }

  const float SCL = 0.18033688011112042f;  // log2(e) / sqrt(HD)

  for (int kt = 0; kt < S / 64; ++kt) {
    const int kk0 = kt * 64;

    // V tile -> regs (issued early; each wave owns 16 d-columns)
    bf16x8 vv[2];
#pragma unroll
    for (int sI = 0; sI < 2; ++sI)
      vv[sI] = *(const bf16x8*)&V[(kk0 + lane) * HD + w * 8 + sI * 32];

    // QK^T: both operands K-contiguous -> fragments straight from global (L1/L2)
    f32x4 sa[2][4];
#pragma unroll
    for (int mt = 0; mt < 2; ++mt)
#pragma unroll
      for (int nt = 0; nt < 4; ++nt) sa[mt][nt] = fz;
#pragma unroll
    for (int ks = 0; ks < 2; ++ks) {
      bf16x8 kf[4];
#pragma unroll
      for (int nt = 0; nt < 4; ++nt)
        kf[nt] = *(const bf16x8*)&K[(kk0 + nt * 16 + c) * HD + ks * 32 + g * 8];
#pragma unroll
      for (int mt = 0; mt < 2; ++mt)
#pragma unroll
        for (int nt = 0; nt < 4; ++nt)
          sa[mt][nt] = MFMA16(qf[mt][ks], kf[nt], sa[mt][nt]);
    }

    __syncthreads();  // all waves done reading previous Vt
    // transpose-write V tile: Vt[d][kk]
#pragma unroll
    for (int sI = 0; sI < 2; ++sI)
#pragma unroll
      for (int jj = 0; jj < 8; ++jj)
        Vt[(w * 8 + sI * 32 + jj) * 72 + lane] = vv[sI][jj];

    // online softmax (wave-parallel: 4-nt in-lane + 16-lane shfl reduce)
#pragma unroll
    for (int mt = 0; mt < 2; ++mt) {
#pragma unroll
      for (int r = 0; r < 4; ++r) {
        float mx = fmaxf(fmaxf(sa[mt][0][r], sa[mt][1][r]),
                         fmaxf(sa[mt][2][r], sa[mt][3][r]));
#pragma unroll
        for (int off = 1; off < 16; off <<= 1)
          mx = fmaxf(mx, __shfl_xor(mx, off, 64));
        const float mn = fmaxf(mst[mt][r], mx * SCL);
        const float corr = exp2f(mst[mt][r] - mn);
        float rs = 0.f;
#pragma unroll
        for (int nt = 0; nt < 4; ++nt) {
          float p = exp2f(sa[mt][nt][r] * SCL - mn);
          sa[mt][nt][r] = p;
          rs += p;
        }
#pragma unroll
        for (int off = 1; off < 16; off <<= 1)
          rs += __shfl_xor(rs, off, 64);
        lst[mt][r] = lst[mt][r] * corr + rs;
        mst[mt][r] = mn;
#pragma unroll
        for (int nt = 0; nt < 4; ++nt) o[mt][nt][r] *= corr;
      }
    }

    // P -> per-wave LDS (C-layout write, A-frag-layout read)
#pragma unroll
    for (int mt = 0; mt < 2; ++mt)
#pragma unroll
      for (int nt = 0; nt < 4; ++nt)
#pragma unroll
        for (int r = 0; r < 4; ++r)
          Pl[w][(mt * 16 + g * 4 + r) * 72 + nt * 16 + c] = f2b(sa[mt][nt][r]);

    __syncthreads();  // Vt fully written

    // PV: o += P @ V
#pragma unroll
    for (int ks = 0; ks < 2; ++ks) {
      bf16x8 pa[2], vf[4];
#pragma unroll
      for (int mt = 0; mt < 2; ++mt)
        pa[mt] = *(const bf16x8*)&Pl[w][(mt * 16 + c) * 72 + ks * 32 + g * 8];
#pragma unroll
      for (int nt = 0; nt < 4; ++nt)
        vf[nt] = *(const bf16x8*)&Vt[(nt * 16 + c) * 72 + ks * 32 + g * 8];
#pragma unroll
      for (int mt = 0; mt < 2; ++mt)
#pragma unroll
        for (int nt = 0; nt < 4; ++nt)
          o[mt][nt] = MFMA16(pa[mt], vf[nt], o[mt][nt]);
    }
  }

  // epilogue: att[b*S + q][h*HD + d] = o / l   (bf16, [B*S, D] row-major)
#pragma unroll
  for (int mt = 0; mt < 2; ++mt) {
#pragma unroll
    for (int r = 0; r < 4; ++r) {
      const float inv = 1.f / lst[mt][r];
      const int row = b * S + qt * 128 + w * 32 + mt * 16 + g * 4 + r;
#pragma unroll
      for (int nt = 0; nt < 4; ++nt) {
        const int col = h * HD + nt * 16 + c;
        att[row * DMODEL + col] = f2b(o[mt][nt][r] * inv);
      }
    }
  }
}

extern "C" void kernel_launch(void* const* d_in, const int* in_sizes, int n_in,
                              void* d_out, int out_size, void* d_ws, size_t ws_size,
                              hipStream_t stream) {
  const float* query = (const float*)d_in[0];
  const float* key_  = (const float*)d_in[1];
  const float* value = (const float*)d_in[2];
  const float* Wq = (const float*)d_in[3];
  const float* bq = (const float*)d_in[4];
  const float* Wk = (const float*)d_in[5];
  const float* bk = (const float*)d_in[6];
  const float* Wv = (const float*)d_in[7];
  const float* bv = (const float*)d_in[8];
  const float* Wo = (const float*)d_in[9];
  const float* bo = (const float*)d_in[10];
  float* out = (float*)d_out;

  char* ws = (char*)d_ws;
  const size_t WB_BYTES  = (size_t)4 * DMODEL * DMODEL * 2;  // 2 MiB
  const size_t MAT_BYTES = (size_t)M * DMODEL * 2;           // 8 MiB each
  short* Wb  = (short*)ws;
  short* Qp  = (short*)(ws + WB_BYTES);
  short* Kp  = (short*)(ws + WB_BYTES + MAT_BYTES);
  short* Vp  = (short*)(ws + WB_BYTES + 2 * MAT_BYTES);
  short* att = (short*)(ws + WB_BYTES + 3 * MAT_BYTES);

  convert_w<<<dim3(128, 4), 256, 0, stream>>>(Wq, Wk, Wv, Wo, Wb);
  proj_gemm<<<dim3(256, 3), 256, 0, stream>>>(query, key_, value, Wb, bq, bk, bv, Qp, Kp, Vp);
  attn_kernel<<<dim3(512), 256, 0, stream>>>(Qp, Kp, Vp, att);
  out_gemm<<<dim3(256), 256, 0, stream>>>(att, Wb + 3 * DMODEL * DMODEL, bo, out);
}

// Round 3
// 127.258 us; speedup vs baseline: 1.5567x; 1.5567x over previous
//
#include <hip/hip_runtime.h>
#include <hip/hip_bf16.h>

typedef __attribute__((ext_vector_type(8))) short bf16x8;
typedef __attribute__((ext_vector_type(4))) float f32x4;
typedef __attribute__((ext_vector_type(16))) float f32x16;
typedef __attribute__((ext_vector_type(4))) unsigned int u32x4;

#define MFMA16(a, b, c) __builtin_amdgcn_mfma_f32_16x16x32_bf16((a), (b), (c), 0, 0, 0)
#define MFMA32(a, b, c) __builtin_amdgcn_mfma_f32_32x32x16_bf16((a), (b), (c), 0, 0, 0)

static constexpr int BATCH = 4, S = 2048, DMODEL = 512, H = 8, HD = 64;
static constexpr int M = BATCH * S;  // 8192

// round-to-nearest-even f32 -> bf16 (bit trick; inputs finite)
__device__ __forceinline__ short f2b(float f) {
  unsigned int u = __builtin_bit_cast(unsigned int, f);
  unsigned int r = (u + 0x7fffu + ((u >> 16) & 1u)) >> 16;
  return (short)r;
}

__device__ __forceinline__ bf16x8 cvt8(const float4& a, const float4& b) {
  bf16x8 r;
  r[0] = f2b(a.x); r[1] = f2b(a.y); r[2] = f2b(a.z); r[3] = f2b(a.w);
  r[4] = f2b(b.x); r[5] = f2b(b.y); r[6] = f2b(b.z); r[7] = f2b(b.w);
  return r;
}

// ---------------- weight fp32 -> bf16 ----------------
__global__ __launch_bounds__(256) void convert_w(
    const float* __restrict__ Wq, const float* __restrict__ Wk,
    const float* __restrict__ Wv, const float* __restrict__ Wo,
    short* __restrict__ Wb) {
  const float* src = (blockIdx.y == 0) ? Wq : (blockIdx.y == 1) ? Wk
                   : (blockIdx.y == 2) ? Wv : Wo;
  short* dst = Wb + blockIdx.y * (DMODEL * DMODEL);
  int i = (blockIdx.x * 256 + threadIdx.x) * 8;
  float4 a = *(const float4*)&src[i];
  float4 b = *(const float4*)&src[i + 4];
  *(bf16x8*)&dst[i] = cvt8(a, b);
}

// ---------------- fused Q/K/V projection: C = A @ W^T + b, scatter [B,H,S,HD] bf16 ----------------
__global__ __launch_bounds__(256) void proj_gemm(
    const float* __restrict__ Aq, const float* __restrict__ Ak, const float* __restrict__ Av,
    const short* __restrict__ Wb,
    const float* __restrict__ bq, const float* __restrict__ bk, const float* __restrict__ bv,
    short* __restrict__ Qp, short* __restrict__ Kp, short* __restrict__ Vp) {
  const int which = blockIdx.y;
  const float* A    = (which == 0) ? Aq : (which == 1) ? Ak : Av;
  const short* W    = Wb + which * (DMODEL * DMODEL);
  const float* bias = (which == 0) ? bq : (which == 1) ? bk : bv;
  short* dst        = (which == 0) ? Qp : (which == 1) ? Kp : Vp;

  const int tm = blockIdx.x & 63;
  const int tn = blockIdx.x >> 6;
  const int m0 = tm * 128, n0 = tn * 128;
  const int t = threadIdx.x;
  const int lane = t & 63, w = t >> 6;
  const int g = lane >> 4, c = lane & 15;
  const int wr = w >> 1, wc = w & 1;

  __shared__ __align__(16) short As[128 * 32];
  __shared__ __align__(16) short Bs[128 * 32];

  f32x4 acc[4][4];
  const f32x4 fz = {0.f, 0.f, 0.f, 0.f};
#pragma unroll
  for (int i = 0; i < 4; ++i)
#pragma unroll
    for (int j = 0; j < 4; ++j) acc[i][j] = fz;

  const int r0 = t >> 2, c0 = (t & 3) * 8;
  const int r1 = (t + 256) >> 2;

  for (int kt = 0; kt < DMODEL / 32; ++kt) {
    const int k0 = kt * 32;
    float4 a0 = *(const float4*)&A[(m0 + r0) * DMODEL + k0 + c0];
    float4 a1 = *(const float4*)&A[(m0 + r0) * DMODEL + k0 + c0 + 4];
    float4 a2 = *(const float4*)&A[(m0 + r1) * DMODEL + k0 + c0];
    float4 a3 = *(const float4*)&A[(m0 + r1) * DMODEL + k0 + c0 + 4];
    bf16x8 b0 = *(const bf16x8*)&W[(n0 + r0) * DMODEL + k0 + c0];
    bf16x8 b1 = *(const bf16x8*)&W[(n0 + r1) * DMODEL + k0 + c0];
    __syncthreads();
    *(bf16x8*)&As[t * 8]        = cvt8(a0, a1);
    *(bf16x8*)&As[t * 8 + 2048] = cvt8(a2, a3);
    *(bf16x8*)&Bs[t * 8]        = b0;
    *(bf16x8*)&Bs[t * 8 + 2048] = b1;
    __syncthreads();
    bf16x8 af[4], bfr[4];
#pragma unroll
    for (int i = 0; i < 4; ++i)
      af[i] = *(const bf16x8*)&As[(wr * 64 + i * 16 + c) * 32 + g * 8];
#pragma unroll
    for (int j = 0; j < 4; ++j)
      bfr[j] = *(const bf16x8*)&Bs[(wc * 64 + j * 16 + c) * 32 + g * 8];
#pragma unroll
    for (int i = 0; i < 4; ++i)
#pragma unroll
      for (int j = 0; j < 4; ++j)
        acc[i][j] = MFMA16(af[i], bfr[j], acc[i][j]);
  }

#pragma unroll
  for (int i = 0; i < 4; ++i) {
#pragma unroll
    for (int j = 0; j < 4; ++j) {
      const int n = n0 + wc * 64 + j * 16 + c;
      const int h = n >> 6, hd = n & 63;
      const float bn = bias[n];
#pragma unroll
      for (int r = 0; r < 4; ++r) {
        const int m = m0 + wr * 64 + i * 16 + g * 4 + r;
        const int bb = m >> 11, s = m & (S - 1);
        dst[((bb * H + h) * S + s) * HD + hd] = f2b(acc[i][j][r] + bn);
      }
    }
  }
}

// ---------------- output GEMM: Out = att @ Wo^T + bo (fp32 out) ----------------
__global__ __launch_bounds__(256) void out_gemm(
    const short* __restrict__ Am, const short* __restrict__ W,
    const float* __restrict__ bias, float* __restrict__ Out) {
  const int tm = blockIdx.x & 63;
  const int tn = blockIdx.x >> 6;
  const int m0 = tm * 128, n0 = tn * 128;
  const int t = threadIdx.x;
  const int lane = t & 63, w = t >> 6;
  const int g = lane >> 4, c = lane & 15;
  const int wr = w >> 1, wc = w & 1;

  __shared__ __align__(16) short As[128 * 32];
  __shared__ __align__(16) short Bs[128 * 32];

  f32x4 acc[4][4];
  const f32x4 fz = {0.f, 0.f, 0.f, 0.f};
#pragma unroll
  for (int i = 0; i < 4; ++i)
#pragma unroll
    for (int j = 0; j < 4; ++j) acc[i][j] = fz;

  const int r0 = t >> 2, c0 = (t & 3) * 8;
  const int r1 = (t + 256) >> 2;

  for (int kt = 0; kt < DMODEL / 32; ++kt) {
    const int k0 = kt * 32;
    bf16x8 a0 = *(const bf16x8*)&Am[(m0 + r0) * DMODEL + k0 + c0];
    bf16x8 a1 = *(const bf16x8*)&Am[(m0 + r1) * DMODEL + k0 + c0];
    bf16x8 b0 = *(const bf16x8*)&W[(n0 + r0) * DMODEL + k0 + c0];
    bf16x8 b1 = *(const bf16x8*)&W[(n0 + r1) * DMODEL + k0 + c0];
    __syncthreads();
    *(bf16x8*)&As[t * 8]        = a0;
    *(bf16x8*)&As[t * 8 + 2048] = a1;
    *(bf16x8*)&Bs[t * 8]        = b0;
    *(bf16x8*)&Bs[t * 8 + 2048] = b1;
    __syncthreads();
    bf16x8 af[4], bfr[4];
#pragma unroll
    for (int i = 0; i < 4; ++i)
      af[i] = *(const bf16x8*)&As[(wr * 64 + i * 16 + c) * 32 + g * 8];
#pragma unroll
    for (int j = 0; j < 4; ++j)
      bfr[j] = *(const bf16x8*)&Bs[(wc * 64 + j * 16 + c) * 32 + g * 8];
#pragma unroll
    for (int i = 0; i < 4; ++i)
#pragma unroll
      for (int j = 0; j < 4; ++j)
        acc[i][j] = MFMA16(af[i], bfr[j], acc[i][j]);
  }

#pragma unroll
  for (int i = 0; i < 4; ++i) {
#pragma unroll
    for (int j = 0; j < 4; ++j) {
      const int n = n0 + wc * 64 + j * 16 + c;
      const float bn = bias[n];
#pragma unroll
      for (int r = 0; r < 4; ++r) {
        const int m = m0 + wr * 64 + i * 16 + g * 4 + r;
        Out[m * DMODEL + n] = acc[i][j][r] + bn;
      }
    }
  }
}

// ---------------- flash attention, swapped-QK^T 32x32, in-register softmax ----------------
// Per block: 4 waves x 32 q-rows = 128 q-tile. Per wave-lane: q = lane&31,
// kv-halves split across hi = lane>>5. KVBLK = 64 per iteration.
__global__ __launch_bounds__(256, 2) void attn_kernel(
    const short* __restrict__ Qp, const short* __restrict__ Kp,
    const short* __restrict__ Vp, short* __restrict__ att) {
  const int bid = blockIdx.x;
  const int swz = (bid & 7) * 64 + (bid >> 3);  // 512 % 8 == 0: bijective
  const int qt = swz & 15;
  const int bh = swz >> 4;
  const int b = bh >> 3, h = bh & 7;
  const short* Q = Qp + bh * (S * HD);
  const short* K = Kp + bh * (S * HD);
  const short* V = Vp + bh * (S * HD);

  const int t = threadIdx.x;
  const int lane = t & 63, w = t >> 6;
  const int l31 = lane & 31, hi = lane >> 5;
  const int q0 = qt * 128 + w * 32;

  __shared__ __align__(16) short Vt[2 * 64 * 72];  // double-buffered V^T [d][kv], pitch 72

  // Q B-frags (col = q = lane&31, k = hd = ks*16 + hi*8 + j)
  bf16x8 qf[4];
#pragma unroll
  for (int ks = 0; ks < 4; ++ks)
    qf[ks] = *(const bf16x8*)&Q[(q0 + l31) * HD + ks * 16 + hi * 8];

  f32x16 o0, o1;  // o^T accumulators: col = q = lane&31, row = d
#pragma unroll
  for (int i = 0; i < 16; ++i) { o0[i] = 0.f; o1[i] = 0.f; }
  float mst = -1e30f, lst = 0.f;

  // prologue: K frags (A: row = kv = lane&31 (+32*tt), k = hd) and V rows
  bf16x8 kf[8], vv[2];
#pragma unroll
  for (int tt = 0; tt < 2; ++tt)
#pragma unroll
    for (int ks = 0; ks < 4; ++ks)
      kf[tt * 4 + ks] = *(const bf16x8*)&K[(tt * 32 + l31) * HD + ks * 16 + hi * 8];
#pragma unroll
  for (int sI = 0; sI < 2; ++sI)
    vv[sI] = *(const bf16x8*)&V[lane * HD + w * 16 + sI * 8];
#pragma unroll
  for (int sI = 0; sI < 2; ++sI)
#pragma unroll
    for (int jj = 0; jj < 8; ++jj)
      Vt[(w * 16 + sI * 8 + jj) * 72 + lane] = vv[sI][jj];
  asm volatile("s_waitcnt lgkmcnt(0)" ::: "memory");
  __builtin_amdgcn_s_barrier();
  __builtin_amdgcn_sched_barrier(0);

  const float SCL = 0.18033688011112042f;  // log2(e)/sqrt(HD)

  for (int kt = 0; kt < 32; ++kt) {
    const int curb = (kt & 1) * 4608;

    // QK^T swapped: S^T[kv][q] (row = kv via (reg&3)+8*(reg>>2)+4*hi, col = q = lane&31)
    f32x16 sa0, sa1;
#pragma unroll
    for (int i = 0; i < 16; ++i) { sa0[i] = 0.f; sa1[i] = 0.f; }
#pragma unroll
    for (int ks = 0; ks < 4; ++ks) {
      sa0 = MFMA32(kf[ks],     qf[ks], sa0);
      sa1 = MFMA32(kf[4 + ks], qf[ks], sa1);
    }

    // async prefetch of next K/V tile (hides under softmax + PV)
    const int kkn = ((kt < 31) ? (kt + 1) : 31) * 64;
#pragma unroll
    for (int tt = 0; tt < 2; ++tt)
#pragma unroll
      for (int ks = 0; ks < 4; ++ks)
        kf[tt * 4 + ks] = *(const bf16x8*)&K[(kkn + tt * 32 + l31) * HD + ks * 16 + hi * 8];
#pragma unroll
    for (int sI = 0; sI < 2; ++sI)
      vv[sI] = *(const bf16x8*)&V[(kkn + lane) * HD + w * 16 + sI * 8];

    // ---- in-register online softmax (per-lane q, kv split across hi) ----
    float tm[16];
#pragma unroll
    for (int i = 0; i < 16; ++i) tm[i] = fmaxf(sa0[i], sa1[i]);
#pragma unroll
    for (int i = 0; i < 8; ++i) tm[i] = fmaxf(tm[i], tm[i + 8]);
#pragma unroll
    for (int i = 0; i < 4; ++i) tm[i] = fmaxf(tm[i], tm[i + 4]);
    tm[0] = fmaxf(fmaxf(tm[0], tm[2]), fmaxf(tm[1], tm[3]));
    const float mx = fmaxf(tm[0], __shfl_xor(tm[0], 32, 64));
    const float mxs = mx * SCL;

    if (!__all(mxs - mst <= 8.0f)) {  // defer-max (T13)
      const float mn = fmaxf(mst, mxs);
      const float corr = exp2f(mst - mn);
      lst *= corr;
#pragma unroll
      for (int i = 0; i < 16; ++i) { o0[i] *= corr; o1[i] *= corr; }
      mst = mn;
    }

#pragma unroll
    for (int i = 0; i < 16; ++i) {
      sa0[i] = exp2f(__builtin_fmaf(sa0[i], SCL, -mst));
      sa1[i] = exp2f(__builtin_fmaf(sa1[i], SCL, -mst));
    }
    float ts[16];
#pragma unroll
    for (int i = 0; i < 16; ++i) ts[i] = sa0[i] + sa1[i];
#pragma unroll
    for (int i = 0; i < 8; ++i) ts[i] = ts[i] + ts[i + 8];
#pragma unroll
    for (int i = 0; i < 4; ++i) ts[i] = ts[i] + ts[i + 4];
    ts[0] = (ts[0] + ts[2]) + (ts[1] + ts[3]);
    lst += ts[0] + __shfl_xor(ts[0], 32, 64);

    // ---- P -> bf16 words; permlane32_swap assembles PV B-frags in-register (T12) ----
    // wrd[i] = pack(sa[2i], sa[2i+1]). For frag at k-slice ks (i0 = (ks&1)*4):
    //   lower lane needs w0,w1 = own wrd[i0+0..1],  w2,w3 = upper's wrd[i0+0..1]
    //   upper lane needs w0,w1 = lower's wrd[i0+2..3], w2,w3 = own wrd[i0+2..3]
    // v_permlane32_swap_b32 A,B: A.upper <-> B.lower. So swap(A=wrd[i0+e], B=wrd[i0+2+e])
    // yields fw[e] = A' and fw[2+e] = B'.
    unsigned int wrd0[8], wrd1[8];
#pragma unroll
    for (int i = 0; i < 8; ++i) {
      asm("v_cvt_pk_bf16_f32 %0, %1, %2" : "=v"(wrd0[i]) : "v"(sa0[2 * i]), "v"(sa0[2 * i + 1]));
      asm("v_cvt_pk_bf16_f32 %0, %1, %2" : "=v"(wrd1[i]) : "v"(sa1[2 * i]), "v"(sa1[2 * i + 1]));
    }

    // PV: o^T += V^T @ P  (A = V^T rows = d, B = P cols = q)
#pragma unroll
    for (int ks = 0; ks < 4; ++ks) {
      const int i0 = (ks & 1) * 4;
      unsigned int a0 = (ks < 2) ? wrd0[i0 + 0] : wrd1[i0 + 0];
      unsigned int b0 = (ks < 2) ? wrd0[i0 + 2] : wrd1[i0 + 2];
      unsigned int a1 = (ks < 2) ? wrd0[i0 + 1] : wrd1[i0 + 1];
      unsigned int b1 = (ks < 2) ? wrd0[i0 + 3] : wrd1[i0 + 3];
      asm("v_permlane32_swap_b32 %0, %1" : "+v"(a0), "+v"(b0));
      asm("v_permlane32_swap_b32 %0, %1" : "+v"(a1), "+v"(b1));
      u32x4 fw;
      fw[0] = a0; fw[1] = a1; fw[2] = b0; fw[3] = b1;
      const bf16x8 pfrag = __builtin_bit_cast(bf16x8, fw);
      const bf16x8 va0 = *(const bf16x8*)&Vt[curb + l31 * 72 + ks * 16 + hi * 8];
      const bf16x8 va1 = *(const bf16x8*)&Vt[curb + (32 + l31) * 72 + ks * 16 + hi * 8];
      o0 = MFMA32(va0, pfrag, o0);
      o1 = MFMA32(va1, pfrag, o1);
    }

    // stage next V tile into the other buffer (T14: loads issued long ago)
    const int nxtb = curb ^ 4608;
#pragma unroll
    for (int sI = 0; sI < 2; ++sI)
#pragma unroll
      for (int jj = 0; jj < 8; ++jj)
        Vt[nxtb + (w * 16 + sI * 8 + jj) * 72 + lane] = vv[sI][jj];

    // lgkm-only wait + raw barrier: K/V global prefetches stay in flight (T4)
    asm volatile("s_waitcnt lgkmcnt(0)" ::: "memory");
    __builtin_amdgcn_s_barrier();
    __builtin_amdgcn_sched_barrier(0);
  }

  // epilogue: att[b*S + q][h*HD + d] = o^T / l  (q = lane&31; d = (reg&3)+8*(reg>>2)+4*hi+32*dt)
  const float inv = 1.0f / lst;
  short* arow = att + (b * S + q0 + l31) * DMODEL + h * HD;
#pragma unroll
  for (int dt = 0; dt < 2; ++dt) {
#pragma unroll
    for (int rr = 0; rr < 4; ++rr) {
      float v0 = (dt ? o1[4 * rr + 0] : o0[4 * rr + 0]) * inv;
      float v1 = (dt ? o1[4 * rr + 1] : o0[4 * rr + 1]) * inv;
      float v2 = (dt ? o1[4 * rr + 2] : o0[4 * rr + 2]) * inv;
      float v3 = (dt ? o1[4 * rr + 3] : o0[4 * rr + 3]) * inv;
      unsigned int w0, w1;
      asm("v_cvt_pk_bf16_f32 %0, %1, %2" : "=v"(w0) : "v"(v0), "v"(v1));
      asm("v_cvt_pk_bf16_f32 %0, %1, %2" : "=v"(w1) : "v"(v2), "v"(v3));
      uint2 pk2;
      pk2.x = w0; pk2.y = w1;
      *(uint2*)&arow[dt * 32 + rr * 8 + hi * 4] = pk2;
    }
  }
}

extern "C" void kernel_launch(void* const* d_in, const int* in_sizes, int n_in,
                              void* d_out, int out_size, void* d_ws, size_t ws_size,
                              hipStream_t stream) {
  const float* query = (const float*)d_in[0];
  const float* key_  = (const float*)d_in[1];
  const float* value = (const float*)d_in[2];
  const float* Wq = (const float*)d_in[3];
  const float* bq = (const float*)d_in[4];
  const float* Wk = (const float*)d_in[5];
  const float* bk = (const float*)d_in[6];
  const float* Wv = (const float*)d_in[7];
  const float* bv = (const float*)d_in[8];
  const float* Wo = (const float*)d_in[9];
  const float* bo = (const float*)d_in[10];
  float* out = (float*)d_out;

  char* ws = (char*)d_ws;
  const size_t WB_BYTES  = (size_t)4 * DMODEL * DMODEL * 2;  // 2 MiB
  const size_t MAT_BYTES = (size_t)M * DMODEL * 2;           // 8 MiB each
  short* Wb  = (short*)ws;
  short* Qp  = (short*)(ws + WB_BYTES);
  short* Kp  = (short*)(ws + WB_BYTES + MAT_BYTES);
  short* Vp  = (short*)(ws + WB_BYTES + 2 * MAT_BYTES);
  short* att = (short*)(ws + WB_BYTES + 3 * MAT_BYTES);

  convert_w<<<dim3(128, 4), 256, 0, stream>>>(Wq, Wk, Wv, Wo, Wb);
  proj_gemm<<<dim3(256, 3), 256, 0, stream>>>(query, key_, value, Wb, bq, bk, bv, Qp, Kp, Vp);
  attn_kernel<<<dim3(512), 256, 0, stream>>>(Qp, Kp, Vp, att);
  out_gemm<<<dim3(256), 256, 0, stream>>>(att, Wb + 3 * DMODEL * DMODEL, bo, out);
}